// Round 10
// baseline (1031.483 us; speedup 1.0000x reference)
//
#include <hip/hip_runtime.h>

#define SS 1024
#define BB 2048
#define NT 256     // 4 waves: 0=L0f, 1=L0b, 2=L1f, 3=L1b
#define GRID 256   // 8 batches/block -> 2048; 1 block/CU, 1 wave/SIMD
#define G8 8
#define ROWW 40              // u16 per LDS row (80 B, 16B-aligned rows)
#define SLOTW (8 * ROWW)     // one ring slot: 8 batch rows
#define BUFW (4 * SLOTW)     // ring depth 4

typedef unsigned int u32;
typedef unsigned short u16;
typedef _Float16 f16x4 __attribute__((ext_vector_type(4)));
typedef _Float16 f16x8 __attribute__((ext_vector_type(8)));
typedef float f32x4 __attribute__((ext_vector_type(4)));
typedef u32 u32x2v __attribute__((ext_vector_type(2)));
typedef __fp16 fp16x2 __attribute__((ext_vector_type(2)));

#define L2E 1.4426950408889634f

// lgkmcnt drain + barrier (vmcnt NOT drained: x prefetch stays in flight)
#define BARRIER() asm volatile("s_waitcnt lgkmcnt(0)\n\ts_barrier" ::: "memory")

#if __has_builtin(__builtin_amdgcn_mfma_f32_16x16x32_f16)
#define HAS32 1
#else
#define HAS32 0
#endif

// ---------- helpers ----------
__device__ __forceinline__ u16 f2bf(float f) {
  u32 u = __float_as_uint(f);
  return (u16)((u + 0x7fffu + ((u >> 16) & 1u)) >> 16);
}
template<bool BFM>
__device__ __forceinline__ float ldin(const void* p, int i) {
  if (BFM) { u16 v = ((const u16*)p)[i]; return __uint_as_float(((u32)v) << 16); }
  return ((const float*)p)[i];
}
__device__ __forceinline__ u32 packrtz(float lo, float hi) {
#if __has_builtin(__builtin_amdgcn_cvt_pkrtz)
  fp16x2 h = __builtin_amdgcn_cvt_pkrtz(lo, hi);
  return __builtin_bit_cast(u32, h);
#else
  _Float16 ha = (_Float16)lo, hb = (_Float16)hi;
  return (u32)__builtin_bit_cast(u16, ha) | ((u32)__builtin_bit_cast(u16, hb) << 16);
#endif
}
template<bool BFM>
__device__ __forceinline__ u32 ldpacks(const void* p, int i, float s) {
  float a, b;
  if (BFM) {
    u32 pr = *(const u32*)((const u16*)p + i);
    a = __uint_as_float(pr << 16);
    b = __uint_as_float(pr & 0xffff0000u);
  } else {
    a = ((const float*)p)[i];
    b = ((const float*)p)[i + 1];
  }
  return packrtz(a * s, b * s);
}
__device__ __forceinline__ float exp2fast(float x) {
#if __has_builtin(__builtin_amdgcn_exp2f)
  return __builtin_amdgcn_exp2f(x);
#else
  return __expf(x * 0.6931471805599453f);
#endif
}
// pre-acts PRE-SCALED: sigmoid gates by -log2e, tanh gate by +2log2e
__device__ __forceinline__ float combine(const float acc[4], float& c) {
  float ig = __builtin_amdgcn_rcpf(1.0f + exp2fast(acc[0]));
  float fg = __builtin_amdgcn_rcpf(1.0f + exp2fast(acc[1]));
  float gg = 1.0f - 2.0f * __builtin_amdgcn_rcpf(1.0f + exp2fast(acc[2]));
  float og = __builtin_amdgcn_rcpf(1.0f + exp2fast(acc[3]));
  c = fg * c + ig * gg;
  float th = 1.0f - 2.0f * __builtin_amdgcn_rcpf(1.0f + exp2fast((2.0f * L2E) * c));
  return og * th;
}
__device__ __forceinline__ u16 f16bits(float x) {
  _Float16 h = (_Float16)x;
  return __builtin_bit_cast(u16, h);
}
#if HAS32
__device__ __forceinline__ f32x4 mfma32(f16x8 a, f16x8 b, f32x4 c) {
  return __builtin_amdgcn_mfma_f32_16x16x32_f16(a, b, c, 0, 0, 0);
}
#else
__device__ __forceinline__ f32x4 mfma16(f16x4 a, f16x4 b, f32x4 c) {
  return __builtin_amdgcn_mfma_f32_16x16x16f16(a, b, c, 0, 0, 0);
}
#endif

// Rings in LDS (u16): buf0=h0f, buf1=h0b, buf2=hf1. Slot = scan&3.
// Row layout: [batch 0..7][cell 0..31 as f16][pad to 40] -> B-frag read is one
// b128 at (bM*ROWW + 8q) u16; publish is 4 scattered b16 writes.
//
// Phases u = 0..SS+1 (one barrier each):
//   L0f/L0b: scan u   (u<SS):    rec = own buf slot (u-1)&3, write slot u&3
//   L1f:     scan u-1 (1<=u<=SS): inp = h0f[(u-1)&3], rec = hf1[(u-2)&3],
//                                 write hf1[(u-1)&3]
//   L1b+head:scan u-2 (u>=2):    inp = h0b[(u-2)&3], rec = hf1[(u-2)&3] (ref
//                                 bug: hb1 uses hf1(s)); head reuses rec frag.
template<bool BFM>
__device__ __forceinline__ void run(
    const void* xg,
    const void* Wih_f0, const void* Whh_f0, const void* b_f0,
    const void* Wih_f1, const void* Whh_f1, const void* b_f1,
    const void* Wih_b0, const void* Whh_b0, const void* b_b0,
    const void* Wih_b1, const void* Whh_b1, const void* b_b1,
    const void* Wlin, const void* blin, const int* futp, void* outp_g,
    u16* hb, int tid, int bid) {
  const int wv = tid >> 6, lane = tid & 63;
  const int m = lane & 15, q = lane >> 4;
  const int bM = m & 7, half = m >> 3;
  const int gb8 = bid * G8;
  const bool isL1 = wv >= 2;

  const void* Wr = (wv == 0) ? Whh_f0 : (wv == 1) ? Whh_b0
                 : (wv == 2) ? Whh_f1 : Whh_b1;
  const void* Wi = (wv == 3) ? Wih_b1 : Wih_f1;      // meaningful iff isL1
  const void* pb = (wv == 0) ? b_f0 : (wv == 1) ? b_b0
                 : (wv == 2) ? b_f1 : b_b1;
  const void* px = (wv == 1) ? Wih_b0 : Wih_f0;      // meaningful iff !isL1

  // ---- A-frags, cell-major row permutation: W~row 16T+m -> orig row
  //      R = (m&3)*32 + 4T + (m>>2); k = 8q+j (same sigma for A and B).
  const float sw = ((m & 3) == 2) ? (2.0f * L2E) : (-L2E);
#if HAS32
  f16x8 wr8[8], wi8[8];
#pragma unroll
  for (int t = 0; t < 8; ++t) {
    const int R = (m & 3) * 32 + 4 * t + (m >> 2);
    const int i0 = R * 32 + 8 * q;
    uint4 v;
    v.x = ldpacks<BFM>(Wr, i0 + 0, sw); v.y = ldpacks<BFM>(Wr, i0 + 2, sw);
    v.z = ldpacks<BFM>(Wr, i0 + 4, sw); v.w = ldpacks<BFM>(Wr, i0 + 6, sw);
    wr8[t] = __builtin_bit_cast(f16x8, v);
    v.x = ldpacks<BFM>(Wi, i0 + 0, sw); v.y = ldpacks<BFM>(Wi, i0 + 2, sw);
    v.z = ldpacks<BFM>(Wi, i0 + 4, sw); v.w = ldpacks<BFM>(Wi, i0 + 6, sw);
    wi8[t] = __builtin_bit_cast(f16x8, v);
  }
#else
  f16x4 wr4[8][2], wi4[8][2];
#pragma unroll
  for (int t = 0; t < 8; ++t) {
    const int R = (m & 3) * 32 + 4 * t + (m >> 2);
#pragma unroll
    for (int s = 0; s < 2; ++s) {
      const int i0 = R * 32 + 16 * s + 4 * q;
      u32x2v v;
      v.x = ldpacks<BFM>(Wr, i0, sw); v.y = ldpacks<BFM>(Wr, i0 + 2, sw);
      wr4[t][s] = __builtin_bit_cast(f16x4, v);
      v.x = ldpacks<BFM>(Wi, i0, sw); v.y = ldpacks<BFM>(Wi, i0 + 2, sw);
      wi4[t][s] = __builtin_bit_cast(f16x4, v);
    }
  }
#endif
  // ---- per-lane duty: 4 cells = 4(T0+k)+q, T0 = half*4 ----
  int cc[4];
  float bv[4][4], wxv[4][4], cs[4], wlb[4], wlf[8];
#pragma unroll
  for (int k = 0; k < 4; ++k) {
    cc[k] = 4 * (half * 4 + k) + q;
    cs[k] = 0.f;
#pragma unroll
    for (int r = 0; r < 4; ++r) {
      const float sg = (r == 2) ? (2.0f * L2E) : (-L2E);
      bv[k][r] = ldin<BFM>(pb, r * 32 + cc[k]) * sg;
      wxv[k][r] = (!isL1) ? ldin<BFM>(px, r * 32 + cc[k]) * sg : 0.f;
    }
    wlb[k] = (wv == 3) ? ldin<BFM>(Wlin, 32 + cc[k]) : 0.f;
  }
#pragma unroll
  for (int j = 0; j < 8; ++j) {
#if HAS32
    const int cf = 8 * q + j;
#else
    const int cf = (j < 4) ? (4 * q + j) : (16 + 4 * q + j - 4);
#endif
    wlf[j] = (wv == 3 && m < 8) ? ldin<BFM>(Wlin, cf) : 0.f;
  }
  const float blv = ldin<BFM>(blin, 0);
  const int fut = *futp;

  // zero rings (scan -1/-2 reads hit zeros)
  {
    u32* hz = (u32*)hb;
    for (int i = tid; i < 3 * BUFW / 2; i += NT) hz[i] = 0u;
  }
  __syncthreads();

  float x_cur = 0.f;
  if (!isL1)
    x_cur = ldin<BFM>(xg, ((wv == 1) ? (fut & (SS - 1)) : 0) * BB + gb8 + bM);

  for (int u = 0; u <= SS + 1; ++u) {
    const int s1 = (u + 3) & 3;   // (u-1)&3
    const int s2 = (u + 2) & 3;   // (u-2)&3
    float x_nxt = 0.f;
    if (!isL1) {
      const int ni = (wv == 1) ? ((fut - (u + 1)) & (SS - 1))
                               : ((u + 1 < SS) ? u + 1 : SS - 1);
      x_nxt = ldin<BFM>(xg, ni * BB + gb8 + bM);   // in flight across barrier
    }

    // ---- B-frag reads ----
    const u16* pA = (wv == 0) ? (hb + 0 * BUFW + s1 * SLOTW)
                  : (wv == 1) ? (hb + 1 * BUFW + s1 * SLOTW)
                  : (wv == 2) ? (hb + 0 * BUFW + s1 * SLOTW)
                              : (hb + 1 * BUFW + s2 * SLOTW);
    const u16* pR = hb + 2 * BUFW + s2 * SLOTW;    // hf1 ring (L1 only)
    f32x4 D[8];
    const f32x4 z = {0.f, 0.f, 0.f, 0.f};
#if HAS32
    uint4 Araw = *(const uint4*)(pA + bM * ROWW + 8 * q);
    f16x8 BA = __builtin_bit_cast(f16x8, Araw);
    uint4 Rraw = {};
    if (isL1) Rraw = *(const uint4*)(pR + bM * ROWW + 8 * q);
    f16x8 BR = __builtin_bit_cast(f16x8, Rraw);
    if (!isL1) {
#pragma unroll
      for (int t = 0; t < 8; ++t) D[t] = mfma32(wr8[t], BA, z);
    } else {
#pragma unroll
      for (int t = 0; t < 8; ++t)
        D[t] = mfma32(wr8[t], BR, mfma32(wi8[t], BA, z));
    }
#else
    u32x2v Alo = *(const u32x2v*)(pA + bM * ROWW + 4 * q);
    u32x2v Ahi = *(const u32x2v*)(pA + bM * ROWW + 16 + 4 * q);
    f16x4 BA0 = __builtin_bit_cast(f16x4, Alo), BA1 = __builtin_bit_cast(f16x4, Ahi);
    u32x2v Rlo = {}, Rhi = {};
    if (isL1) {
      Rlo = *(const u32x2v*)(pR + bM * ROWW + 4 * q);
      Rhi = *(const u32x2v*)(pR + bM * ROWW + 16 + 4 * q);
    }
    f16x4 BR0 = __builtin_bit_cast(f16x4, Rlo), BR1 = __builtin_bit_cast(f16x4, Rhi);
    if (!isL1) {
#pragma unroll
      for (int t = 0; t < 8; ++t)
        D[t] = mfma16(wr4[t][1], BA1, mfma16(wr4[t][0], BA0, z));
    } else {
#pragma unroll
      for (int t = 0; t < 8; ++t) {
        f32x4 a = mfma16(wi4[t][1], BA1, mfma16(wi4[t][0], BA0, z));
        D[t] = mfma16(wr4[t][1], BR1, mfma16(wr4[t][0], BR0, a));
      }
    }
#endif

    // ---- combine (4 cells/lane, static D indices + half-select) ----
    const bool act = (!isL1) ? (u < SS)
                   : (wv == 2) ? (u >= 1 && u <= SS) : (u >= 2);
    if (act) {
      float hh[4];
#pragma unroll
      for (int k = 0; k < 4; ++k) {
        float acc[4];
#pragma unroll
        for (int r = 0; r < 4; ++r) {
          float dv = half ? D[k + 4][r] : D[k][r];
          acc[r] = dv + ((!isL1) ? fmaf(wxv[k][r], x_cur, bv[k][r]) : bv[k][r]);
        }
        hh[k] = combine(acc, cs[k]);
      }
      if (wv != 3) {
        const int wslot = (!isL1) ? (u & 3) : s1;     // = scan&3
        const int wb = (wv == 2) ? 2 : wv;
        u16* wp = hb + wb * BUFW + wslot * SLOTW + bM * ROWW;
#pragma unroll
        for (int k = 0; k < 4; ++k) wp[cc[k]] = f16bits(hh[k]);
      } else {
        // ---- head for scan u-2: wlb.hb1 (own) + wlf.hf1 (rec frag, m<8) ----
        float hv = 0.f;
#pragma unroll
        for (int k = 0; k < 4; ++k) hv = fmaf(wlb[k], hh[k], hv);
#if HAS32
        f16x8 bf = __builtin_bit_cast(f16x8, Rraw);
#pragma unroll
        for (int j = 0; j < 8; ++j) hv = fmaf(wlf[j], (float)bf[j], hv);
#else
#pragma unroll
        for (int j = 0; j < 4; ++j) {
          hv = fmaf(wlf[j], (float)BR0[j], hv);
          hv = fmaf(wlf[4 + j], (float)BR1[j], hv);
        }
#endif
        hv += __shfl_xor(hv, 8, 64);
        hv += __shfl_xor(hv, 16, 64);
        hv += __shfl_xor(hv, 32, 64);
        if (lane < 8) {
          float o = hv + blv;
          size_t pos = (size_t)(gb8 + lane) * SS + (size_t)(u - 2);
          if (BFM) ((u16*)outp_g)[pos] = f2bf(o);
          else     ((float*)outp_g)[pos] = o;
        }
      }
    }
    BARRIER();
    x_cur = x_nxt;
  }
}

// 4 waves, 1 wave/SIMD target; min 1 wave/EU -> full VGPR budget available.
__global__ void __launch_bounds__(NT, 1) lstm_kernel(
    const void* __restrict__ xg,
    const void* Wih_f0, const void* Whh_f0, const void* b_f0,
    const void* Wih_f1, const void* Whh_f1, const void* b_f1,
    const void* Wih_b0, const void* Whh_b0, const void* b_b0,
    const void* Wih_b1, const void* Whh_b1, const void* b_b1,
    const void* Wlin, const void* blin, const int* __restrict__ futp,
    void* __restrict__ outp) {
  __shared__ __align__(16) u16 hbs[3 * BUFW];

  // dtype detection (uniform): bf16-pairs read as fp32 implausible as N(0,1)
  bool bfm;
  {
    const float* xf = (const float*)xg;
    int bad = 0;
    for (int i = 0; i < 64; ++i) {
      float a = fabsf(xf[i]);
      bool ok = (a == 0.0f) || (a > 1e-8f && a < 1e4f);
      if (!ok) bad = 1;
    }
    bfm = (bad != 0);
  }

  if (bfm)
    run<true>(xg, Wih_f0, Whh_f0, b_f0, Wih_f1, Whh_f1, b_f1,
              Wih_b0, Whh_b0, b_b0, Wih_b1, Whh_b1, b_b1,
              Wlin, blin, futp, outp, hbs, threadIdx.x, blockIdx.x);
  else
    run<false>(xg, Wih_f0, Whh_f0, b_f0, Wih_f1, Whh_f1, b_f1,
               Wih_b0, Whh_b0, b_b0, Wih_b1, Whh_b1, b_b1,
               Wlin, blin, futp, outp, hbs, threadIdx.x, blockIdx.x);
}

extern "C" void kernel_launch(void* const* d_in, const int* in_sizes, int n_in,
                              void* d_out, int out_size, void* d_ws, size_t ws_size,
                              hipStream_t stream) {
  (void)in_sizes; (void)n_in; (void)out_size; (void)d_ws; (void)ws_size;
  lstm_kernel<<<dim3(GRID), dim3(NT), 0, stream>>>(
      d_in[0], d_in[1], d_in[2], d_in[3], d_in[4], d_in[5], d_in[6],
      d_in[7], d_in[8], d_in[9], d_in[10], d_in[11], d_in[12],
      d_in[13], d_in[14], (const int*)d_in[15], d_out);
}

// Round 11
// 997.938 us; speedup vs baseline: 1.0336x; 1.0336x over previous
//
#include <hip/hip_runtime.h>

#define SS 1024
#define BB 2048
#define NT 256     // 4 waves: 0=L0f, 1=L0b, 2=L1f, 3=L1b
#define GRID 512   // 4 batches/block -> 2048; 2 blocks/CU -> 2 waves/SIMD
#define G4 4
#define ROWW 40              // u16 per LDS row (80 B, 16B-aligned rows)
#define SLOTW (4 * ROWW)     // one ring slot: 4 batch rows
#define BUFW (4 * SLOTW)     // ring depth 4

typedef unsigned int u32;
typedef unsigned short u16;
typedef _Float16 f16x4 __attribute__((ext_vector_type(4)));
typedef _Float16 f16x8 __attribute__((ext_vector_type(8)));
typedef float f32x4 __attribute__((ext_vector_type(4)));
typedef u32 u32x2v __attribute__((ext_vector_type(2)));
typedef __fp16 fp16x2 __attribute__((ext_vector_type(2)));

#define L2E 1.4426950408889634f

// lgkmcnt drain + barrier (vmcnt NOT drained: x prefetch stays in flight)
#define BARRIER() asm volatile("s_waitcnt lgkmcnt(0)\n\ts_barrier" ::: "memory")

#if __has_builtin(__builtin_amdgcn_mfma_f32_16x16x32_f16)
#define HAS32 1
#else
#define HAS32 0
#endif

// ---------- helpers ----------
__device__ __forceinline__ u16 f2bf(float f) {
  u32 u = __float_as_uint(f);
  return (u16)((u + 0x7fffu + ((u >> 16) & 1u)) >> 16);
}
template<bool BFM>
__device__ __forceinline__ float ldin(const void* p, int i) {
  if (BFM) { u16 v = ((const u16*)p)[i]; return __uint_as_float(((u32)v) << 16); }
  return ((const float*)p)[i];
}
__device__ __forceinline__ u32 packrtz(float lo, float hi) {
#if __has_builtin(__builtin_amdgcn_cvt_pkrtz)
  fp16x2 h = __builtin_amdgcn_cvt_pkrtz(lo, hi);
  return __builtin_bit_cast(u32, h);
#else
  _Float16 ha = (_Float16)lo, hb = (_Float16)hi;
  return (u32)__builtin_bit_cast(u16, ha) | ((u32)__builtin_bit_cast(u16, hb) << 16);
#endif
}
template<bool BFM>
__device__ __forceinline__ u32 ldpacks(const void* p, int i, float s) {
  float a, b;
  if (BFM) {
    u32 pr = *(const u32*)((const u16*)p + i);
    a = __uint_as_float(pr << 16);
    b = __uint_as_float(pr & 0xffff0000u);
  } else {
    a = ((const float*)p)[i];
    b = ((const float*)p)[i + 1];
  }
  return packrtz(a * s, b * s);
}
__device__ __forceinline__ float exp2fast(float x) {
#if __has_builtin(__builtin_amdgcn_exp2f)
  return __builtin_amdgcn_exp2f(x);
#else
  return __expf(x * 0.6931471805599453f);
#endif
}
// pre-acts PRE-SCALED: sigmoid gates by -log2e, tanh gate by +2log2e
__device__ __forceinline__ float combine(const float acc[4], float& c) {
  float ig = __builtin_amdgcn_rcpf(1.0f + exp2fast(acc[0]));
  float fg = __builtin_amdgcn_rcpf(1.0f + exp2fast(acc[1]));
  float gg = 1.0f - 2.0f * __builtin_amdgcn_rcpf(1.0f + exp2fast(acc[2]));
  float og = __builtin_amdgcn_rcpf(1.0f + exp2fast(acc[3]));
  c = fg * c + ig * gg;
  float th = 1.0f - 2.0f * __builtin_amdgcn_rcpf(1.0f + exp2fast((2.0f * L2E) * c));
  return og * th;
}
__device__ __forceinline__ u16 f16bits(float x) {
  _Float16 h = (_Float16)x;
  return __builtin_bit_cast(u16, h);
}
#if HAS32
__device__ __forceinline__ f32x4 mfma32(f16x8 a, f16x8 b, f32x4 c) {
  return __builtin_amdgcn_mfma_f32_16x16x32_f16(a, b, c, 0, 0, 0);
}
#else
__device__ __forceinline__ f32x4 mfma16(f16x4 a, f16x4 b, f32x4 c) {
  return __builtin_amdgcn_mfma_f32_16x16x16f16(a, b, c, 0, 0, 0);
}
#endif

// Rings in LDS (u16): buf0=h0f, buf1=h0b, buf2=hf1. Slot = scan&3.
// Row layout: [batch 0..3][cell 0..31 f16][pad to 40] -> B-frag read = one b128
// at (bM*ROWW + 8q); B cols are x4-duplicated (col m reads batch m&3: LDS
// same-address broadcast, conflict-free). Publish = 2 scattered b16 writes.
//
// Phases u = 0..SS+1 (one barrier each), same ring algebra as R9/R10 (passed):
//   L0f/L0b: scan u   (u<SS):     rec = own buf [(u-1)&3], write [u&3]
//   L1f:     scan u-1 (1<=u<=SS): inp = h0f[(u-1)&3], rec = hf1[(u-2)&3],
//                                 write hf1[(u-1)&3]
//   L1b+head:scan u-2 (u>=2):     inp = h0b[(u-2)&3], rec = hf1[(u-2)&3]
//                                 (ref bug: hb1 uses hf1(s)); head reuses rec.
template<bool BFM>
__device__ __forceinline__ void run(
    const void* xg,
    const void* Wih_f0, const void* Whh_f0, const void* b_f0,
    const void* Wih_f1, const void* Whh_f1, const void* b_f1,
    const void* Wih_b0, const void* Whh_b0, const void* b_b0,
    const void* Wih_b1, const void* Whh_b1, const void* b_b1,
    const void* Wlin, const void* blin, const int* futp, void* outp_g,
    u16* hb, int tid, int bid) {
  const int wv = tid >> 6, lane = tid & 63;
  const int m = lane & 15, q = lane >> 4;
  const int bM = m & 3, g = m >> 2;      // batch, dup-group (owns tiles g, g+4)
  const int gb4 = bid * G4;
  const bool isL1 = wv >= 2;

  const void* Wr = (wv == 0) ? Whh_f0 : (wv == 1) ? Whh_b0
                 : (wv == 2) ? Whh_f1 : Whh_b1;
  const void* Wi = (wv == 3) ? Wih_b1 : Wih_f1;      // meaningful iff isL1
  const void* pb = (wv == 0) ? b_f0 : (wv == 1) ? b_b0
                 : (wv == 2) ? b_f1 : b_b1;
  const void* px = (wv == 1) ? Wih_b0 : Wih_f0;      // meaningful iff !isL1

  // ---- A-frags, cell-major row permutation: W~row 16T+m -> orig row
  //      R = (m&3)*32 + 4T + (m>>2); k = 8q+j (same sigma for A and B).
  const float sw = ((m & 3) == 2) ? (2.0f * L2E) : (-L2E);
#if HAS32
  f16x8 wr8[8], wi8[8];
#pragma unroll
  for (int t = 0; t < 8; ++t) {
    const int R = (m & 3) * 32 + 4 * t + (m >> 2);
    const int i0 = R * 32 + 8 * q;
    uint4 v;
    v.x = ldpacks<BFM>(Wr, i0 + 0, sw); v.y = ldpacks<BFM>(Wr, i0 + 2, sw);
    v.z = ldpacks<BFM>(Wr, i0 + 4, sw); v.w = ldpacks<BFM>(Wr, i0 + 6, sw);
    wr8[t] = __builtin_bit_cast(f16x8, v);
    v.x = ldpacks<BFM>(Wi, i0 + 0, sw); v.y = ldpacks<BFM>(Wi, i0 + 2, sw);
    v.z = ldpacks<BFM>(Wi, i0 + 4, sw); v.w = ldpacks<BFM>(Wi, i0 + 6, sw);
    wi8[t] = __builtin_bit_cast(f16x8, v);
  }
#else
  f16x4 wr4[8][2], wi4[8][2];
#pragma unroll
  for (int t = 0; t < 8; ++t) {
    const int R = (m & 3) * 32 + 4 * t + (m >> 2);
#pragma unroll
    for (int s = 0; s < 2; ++s) {
      const int i0 = R * 32 + 16 * s + 4 * q;
      u32x2v v;
      v.x = ldpacks<BFM>(Wr, i0, sw); v.y = ldpacks<BFM>(Wr, i0 + 2, sw);
      wr4[t][s] = __builtin_bit_cast(f16x4, v);
      v.x = ldpacks<BFM>(Wi, i0, sw); v.y = ldpacks<BFM>(Wi, i0 + 2, sw);
      wi4[t][s] = __builtin_bit_cast(f16x4, v);
    }
  }
#endif
  // ---- per-lane duty: 2 cells = 4*(g + 4k) + q, k = 0,1 (tiles g, g+4) ----
  int cc[2];
  float bv[2][4], wxv[2][4], cs[2], wlb[2], wlf[8];
#pragma unroll
  for (int k = 0; k < 2; ++k) {
    cc[k] = 4 * (g + 4 * k) + q;
    cs[k] = 0.f;
#pragma unroll
    for (int r = 0; r < 4; ++r) {
      const float sg = (r == 2) ? (2.0f * L2E) : (-L2E);
      bv[k][r] = ldin<BFM>(pb, r * 32 + cc[k]) * sg;
      wxv[k][r] = (!isL1) ? ldin<BFM>(px, r * 32 + cc[k]) * sg : 0.f;
    }
    wlb[k] = (wv == 3) ? ldin<BFM>(Wlin, 32 + cc[k]) : 0.f;
  }
#pragma unroll
  for (int j = 0; j < 8; ++j) {
#if HAS32
    const int cf = 8 * q + j;
#else
    const int cf = (j < 4) ? (4 * q + j) : (16 + 4 * q + j - 4);
#endif
    wlf[j] = (wv == 3 && g == 0) ? ldin<BFM>(Wlin, cf) : 0.f;  // count hf1 once
  }
  const float blv = ldin<BFM>(blin, 0);
  const int fut = *futp;

  // zero rings (scan -1/-2 reads hit zeros)
  {
    u32* hz = (u32*)hb;
    for (int i = tid; i < 3 * BUFW / 2; i += NT) hz[i] = 0u;
  }
  __syncthreads();

  float x_cur = 0.f;
  if (!isL1)
    x_cur = ldin<BFM>(xg, ((wv == 1) ? (fut & (SS - 1)) : 0) * BB + gb4 + bM);

  for (int u = 0; u <= SS + 1; ++u) {
    const int s1 = (u + 3) & 3;   // (u-1)&3
    const int s2 = (u + 2) & 3;   // (u-2)&3
    float x_nxt = 0.f;
    if (!isL1) {
      const int ni = (wv == 1) ? ((fut - (u + 1)) & (SS - 1))
                               : ((u + 1 < SS) ? u + 1 : SS - 1);
      x_nxt = ldin<BFM>(xg, ni * BB + gb4 + bM);   // in flight across barrier
    }

    // ---- B-frag reads (col m -> batch m&3 row: broadcast dup) ----
    const u16* pA = (wv == 0) ? (hb + 0 * BUFW + s1 * SLOTW)
                  : (wv == 1) ? (hb + 1 * BUFW + s1 * SLOTW)
                  : (wv == 2) ? (hb + 0 * BUFW + s1 * SLOTW)
                              : (hb + 1 * BUFW + s2 * SLOTW);
    const u16* pR = hb + 2 * BUFW + s2 * SLOTW;    // hf1 ring (L1 only)
    f32x4 D[8];
    const f32x4 z = {0.f, 0.f, 0.f, 0.f};
#if HAS32
    uint4 Araw = *(const uint4*)(pA + bM * ROWW + 8 * q);
    f16x8 BA = __builtin_bit_cast(f16x8, Araw);
    uint4 Rraw = {};
    if (isL1) Rraw = *(const uint4*)(pR + bM * ROWW + 8 * q);
    f16x8 BR = __builtin_bit_cast(f16x8, Rraw);
    if (!isL1) {
#pragma unroll
      for (int t = 0; t < 8; ++t) D[t] = mfma32(wr8[t], BA, z);
    } else {
#pragma unroll
      for (int t = 0; t < 8; ++t)
        D[t] = mfma32(wr8[t], BR, mfma32(wi8[t], BA, z));
    }
#else
    u32x2v Alo = *(const u32x2v*)(pA + bM * ROWW + 4 * q);
    u32x2v Ahi = *(const u32x2v*)(pA + bM * ROWW + 16 + 4 * q);
    f16x4 BA0 = __builtin_bit_cast(f16x4, Alo), BA1 = __builtin_bit_cast(f16x4, Ahi);
    u32x2v Rlo = {}, Rhi = {};
    if (isL1) {
      Rlo = *(const u32x2v*)(pR + bM * ROWW + 4 * q);
      Rhi = *(const u32x2v*)(pR + bM * ROWW + 16 + 4 * q);
    }
    f16x4 BR0 = __builtin_bit_cast(f16x4, Rlo), BR1 = __builtin_bit_cast(f16x4, Rhi);
    if (!isL1) {
#pragma unroll
      for (int t = 0; t < 8; ++t)
        D[t] = mfma16(wr4[t][1], BA1, mfma16(wr4[t][0], BA0, z));
    } else {
#pragma unroll
      for (int t = 0; t < 8; ++t) {
        f32x4 a = mfma16(wi4[t][1], BA1, mfma16(wi4[t][0], BA0, z));
        D[t] = mfma16(wr4[t][1], BR1, mfma16(wr4[t][0], BR0, a));
      }
    }
#endif

    // ---- combine (2 cells/lane; tile pick = static-index cndmask tree) ----
    const bool act = (!isL1) ? (u < SS)
                   : (wv == 2) ? (u >= 1 && u <= SS) : (u >= 2);
    if (act) {
      float hh[2];
#pragma unroll
      for (int k = 0; k < 2; ++k) {
        float acc[4];
#pragma unroll
        for (int r = 0; r < 4; ++r) {
          // D[g + 4k][r] via static indices (rule #20: no runtime array index)
          float d01 = (g & 1) ? D[4 * k + 1][r] : D[4 * k + 0][r];
          float d23 = (g & 1) ? D[4 * k + 3][r] : D[4 * k + 2][r];
          float dv  = (g & 2) ? d23 : d01;
          acc[r] = dv + ((!isL1) ? fmaf(wxv[k][r], x_cur, bv[k][r]) : bv[k][r]);
        }
        hh[k] = combine(acc, cs[k]);
      }
      if (wv != 3) {
        const int wslot = (!isL1) ? (u & 3) : s1;     // = scan&3
        const int wb = (wv == 2) ? 2 : wv;
        u16* wp = hb + wb * BUFW + wslot * SLOTW + bM * ROWW;
        wp[cc[0]] = f16bits(hh[0]);
        wp[cc[1]] = f16bits(hh[1]);
      } else {
        // ---- head for scan u-2: wlb.hb1 (own cells) + wlf.hf1 (g==0 lanes) ----
        float hv = fmaf(wlb[0], hh[0], wlb[1] * hh[1]);
#if HAS32
        f16x8 bf = __builtin_bit_cast(f16x8, Rraw);
#pragma unroll
        for (int j = 0; j < 8; ++j) hv = fmaf(wlf[j], (float)bf[j], hv);
#else
#pragma unroll
        for (int j = 0; j < 4; ++j) {
          hv = fmaf(wlf[j], (float)BR0[j], hv);
          hv = fmaf(wlf[4 + j], (float)BR1[j], hv);
        }
#endif
        // reduce over g (lane bits 2,3) and q (bits 4,5); batch = lane&3
        hv += __shfl_xor(hv, 4, 64);
        hv += __shfl_xor(hv, 8, 64);
        hv += __shfl_xor(hv, 16, 64);
        hv += __shfl_xor(hv, 32, 64);
        if (lane < 4) {
          float o = hv + blv;
          size_t pos = (size_t)(gb4 + lane) * SS + (size_t)(u - 2);
          if (BFM) ((u16*)outp_g)[pos] = f2bf(o);
          else     ((float*)outp_g)[pos] = o;
        }
      }
    }
    BARRIER();
    x_cur = x_nxt;
  }
}

// 4-wave blocks, 2 blocks/CU (GRID=512): each SIMD hosts 2 waves from
// INDEPENDENT barrier groups -> stalls interleave. Min 2 waves/EU -> 128 VGPR.
__global__ void __launch_bounds__(NT, 2) lstm_kernel(
    const void* __restrict__ xg,
    const void* Wih_f0, const void* Whh_f0, const void* b_f0,
    const void* Wih_f1, const void* Whh_f1, const void* b_f1,
    const void* Wih_b0, const void* Whh_b0, const void* b_b0,
    const void* Wih_b1, const void* Whh_b1, const void* b_b1,
    const void* Wlin, const void* blin, const int* __restrict__ futp,
    void* __restrict__ outp) {
  __shared__ __align__(16) u16 hbs[3 * BUFW];

  // dtype detection (uniform): bf16-pairs read as fp32 implausible as N(0,1)
  bool bfm;
  {
    const float* xf = (const float*)xg;
    int bad = 0;
    for (int i = 0; i < 64; ++i) {
      float a = fabsf(xf[i]);
      bool ok = (a == 0.0f) || (a > 1e-8f && a < 1e4f);
      if (!ok) bad = 1;
    }
    bfm = (bad != 0);
  }

  if (bfm)
    run<true>(xg, Wih_f0, Whh_f0, b_f0, Wih_f1, Whh_f1, b_f1,
              Wih_b0, Whh_b0, b_b0, Wih_b1, Whh_b1, b_b1,
              Wlin, blin, futp, outp, hbs, threadIdx.x, blockIdx.x);
  else
    run<false>(xg, Wih_f0, Whh_f0, b_f0, Wih_f1, Whh_f1, b_f1,
               Wih_b0, Whh_b0, b_b0, Wih_b1, Whh_b1, b_b1,
               Wlin, blin, futp, outp, hbs, threadIdx.x, blockIdx.x);
}

extern "C" void kernel_launch(void* const* d_in, const int* in_sizes, int n_in,
                              void* d_out, int out_size, void* d_ws, size_t ws_size,
                              hipStream_t stream) {
  (void)in_sizes; (void)n_in; (void)out_size; (void)d_ws; (void)ws_size;
  lstm_kernel<<<dim3(GRID), dim3(NT), 0, stream>>>(
      d_in[0], d_in[1], d_in[2], d_in[3], d_in[4], d_in[5], d_in[6],
      d_in[7], d_in[8], d_in[9], d_in[10], d_in[11], d_in[12],
      d_in[13], d_in[14], (const int*)d_in[15], d_out);
}

// Round 12
// 739.105 us; speedup vs baseline: 1.3956x; 1.3502x over previous
//
#include <hip/hip_runtime.h>

#define SS 1024
#define BB 2048
#define NT 512     // 8 waves: wv = dir + 2*wq  (dir = wv&1, wq = wv>>1)
#define GRID 256   // 8 batches/block, full 2048; 1 block/CU
#define G8 8
#define ROWDW 20   // u32 per LDS h-row (80 B): b128-aligned, bank-spread

typedef unsigned int u32;
typedef unsigned short u16;
typedef _Float16 f16x4 __attribute__((ext_vector_type(4)));
typedef _Float16 f16x8 __attribute__((ext_vector_type(8)));
typedef float f32x4 __attribute__((ext_vector_type(4)));
typedef u32 u32x2v __attribute__((ext_vector_type(2)));
typedef int int2v __attribute__((ext_vector_type(2)));
typedef __fp16 fp16x2 __attribute__((ext_vector_type(2)));

#define L2E 1.4426950408889634f

// lgkmcnt drain + barrier (vmcnt NOT drained: global x prefetch stays in flight)
#define BARRIER() asm volatile("s_waitcnt lgkmcnt(0)\n\ts_barrier" ::: "memory")

#if __has_builtin(__builtin_amdgcn_mfma_f32_16x16x32_f16)
#define HAS32 1
#else
#define HAS32 0
#endif

// DPP add of cross-lane shifted copy (pure VALU)
#define DPPADD(v, ctrl, rm)                                                   \
  do {                                                                        \
    int _t = __builtin_amdgcn_update_dpp(0, __float_as_int(v), (ctrl), (rm),  \
                                         0xf, true);                          \
    (v) += __int_as_float(_t);                                                \
  } while (0)

// ---------- helpers ----------
__device__ __forceinline__ u16 f2bf(float f) {
  u32 u = __float_as_uint(f);
  return (u16)((u + 0x7fffu + ((u >> 16) & 1u)) >> 16);
}
template<bool BFM>
__device__ __forceinline__ float ldin(const void* p, int i) {
  if (BFM) { u16 v = ((const u16*)p)[i]; return __uint_as_float(((u32)v) << 16); }
  return ((const float*)p)[i];
}
// explicit global-addrspace load: vmcnt-only, survives lgkmcnt barrier drain
template<bool BFM>
__device__ __forceinline__ float ldxg(const void* p, unsigned int i) {
  if (BFM) {
    const __attribute__((address_space(1))) u16* g =
        (const __attribute__((address_space(1))) u16*)(unsigned long long)p;
    return __uint_as_float(((u32)g[i]) << 16);
  }
  const __attribute__((address_space(1))) float* g =
      (const __attribute__((address_space(1))) float*)(unsigned long long)p;
  return g[i];
}
__device__ __forceinline__ u32 packrtz(float lo, float hi) {
#if __has_builtin(__builtin_amdgcn_cvt_pkrtz)
  fp16x2 h = __builtin_amdgcn_cvt_pkrtz(lo, hi);
  return __builtin_bit_cast(u32, h);
#else
  _Float16 ha = (_Float16)lo, hb = (_Float16)hi;
  return (u32)__builtin_bit_cast(u16, ha) | ((u32)__builtin_bit_cast(u16, hb) << 16);
#endif
}
template<bool BFM>
__device__ __forceinline__ u32 ldpacks(const void* p, int i, float s) {
  float a, b;
  if (BFM) {
    u32 pr = *(const u32*)((const u16*)p + i);
    a = __uint_as_float(pr << 16);
    b = __uint_as_float(pr & 0xffff0000u);
  } else {
    a = ((const float*)p)[i];
    b = ((const float*)p)[i + 1];
  }
  return packrtz(a * s, b * s);
}
__device__ __forceinline__ float exp2fast(float x) {
#if __has_builtin(__builtin_amdgcn_exp2f)
  return __builtin_amdgcn_exp2f(x);
#else
  return __expf(x * 0.6931471805599453f);
#endif
}
// pre-acts PRE-SCALED: sigmoid gates by -log2e, tanh gate by +2log2e
__device__ __forceinline__ float combine(const float acc[4], float& c) {
  float ig = __builtin_amdgcn_rcpf(1.0f + exp2fast(acc[0]));
  float fg = __builtin_amdgcn_rcpf(1.0f + exp2fast(acc[1]));
  float gg = 1.0f - 2.0f * __builtin_amdgcn_rcpf(1.0f + exp2fast(acc[2]));
  float og = __builtin_amdgcn_rcpf(1.0f + exp2fast(acc[3]));
  c = fg * c + ig * gg;
  float th = 1.0f - 2.0f * __builtin_amdgcn_rcpf(1.0f + exp2fast((2.0f * L2E) * c));
  return og * th;
}
__device__ __forceinline__ u16 f16bits(float x) {
  _Float16 h = (_Float16)x;
  return __builtin_bit_cast(u16, h);
}
// lane i <- lane i^8 within 16-lane rows (row_ror:8)
__device__ __forceinline__ float dppswap8(float v) {
  int t = __builtin_amdgcn_update_dpp(0, __float_as_int(v), 0x128, 0xf, 0xf, true);
  return __int_as_float(t);
}
// butterfly adds over lane bit 4 / bit 5 — VALU permlane (HW-verified for 32)
__device__ __forceinline__ float plswap16_add(float v) {
#if __has_builtin(__builtin_amdgcn_permlane16_swap)
  int2v r = __builtin_amdgcn_permlane16_swap(__float_as_int(v),
                                             __float_as_int(v), false, false);
  return __int_as_float(r.x) + __int_as_float(r.y);
#else
  return v + __shfl_xor(v, 16, 64);
#endif
}
__device__ __forceinline__ float plswap32_add(float v) {
#if __has_builtin(__builtin_amdgcn_permlane32_swap)
  int2v r = __builtin_amdgcn_permlane32_swap(__float_as_int(v),
                                             __float_as_int(v), false, false);
  return __int_as_float(r.x) + __int_as_float(r.y);
#else
  return v + __shfl_xor(v, 32, 64);
#endif
}
#if HAS32
__device__ __forceinline__ f32x4 mfma32(f16x8 a, f16x8 b, f32x4 c) {
  return __builtin_amdgcn_mfma_f32_16x16x32_f16(a, b, c, 0, 0, 0);
}
#else
__device__ __forceinline__ f32x4 mfma16(f16x4 a, f16x4 b, f32x4 c) {
  return __builtin_amdgcn_mfma_f32_16x16x16f16(a, b, c, 0, 0, 0);
}
#endif

// LDS (batch-major rows, ROWDW=20 dw = 80 B):
//  h0l : [dir][par][16 rows][20 dw]  (f16 h0; rows 8..15 stay zero = junk cols)
//  hf1l: [par][16 rows][20 dw]
//  po  : [par][8 batch][8 wave] f32 head partials (b-major for DPP finalize)
//
// Schedule (ONE barrier/iter) — identical to R7 (passed, 822us):
//   L0 t=u (fwd)/u-1 (bwd): reads h0[par_r], writes h0[par_w]
//   L1 t=u-1 (fwd)/u-2 (bwd): inp = SAME h0[par_r] frags, rec = hf1[par_r];
//      fwd writes hf1[par_w]
//   head partials t=u-2 -> po[par_w]; wave0 emits t=u-3 from po[par_r]
template<bool BFM>
__device__ __forceinline__ void run(
    const void* xg,
    const void* Wih_f0, const void* Whh_f0, const void* b_f0,
    const void* Wih_f1, const void* Whh_f1, const void* b_f1,
    const void* Wih_b0, const void* Whh_b0, const void* b_b0,
    const void* Wih_b1, const void* Whh_b1, const void* b_b1,
    const void* Wlin, const void* blin, const int* futp, void* outp_g,
    u32* h0l, u32* hf1l, float* po, int tid, int bid) {
  const int wv = tid >> 6, lane = tid & 63;
  const int dirv = wv & 1, wq = wv >> 1;
  const int m = lane & 15, q = lane >> 4;
  const int half = m >> 3, bM = m & 7;
  const int gb8 = bid * G8;
  const int xb = gb8 + bM;

  const void* s0  = dirv ? Whh_b0 : Whh_f0;
  const void* sA  = dirv ? Wih_b1 : Wih_f1;
  const void* sB  = dirv ? Whh_b1 : Whh_f1;
  const void* pb0 = dirv ? b_b0 : b_f0;
  const void* pb1 = dirv ? b_b1 : b_f1;
  const void* pwx = dirv ? Wih_b0 : Wih_f0;

  // ---- A-frags, cell-major row permutation (same sigma as R7/R8, verified):
  //      W~ row 16T+m -> orig row R = (m&3)*32 + 4T + (m>>2)
  const int gA = m & 3;
  const float sw = (gA == 2) ? (2.0f * L2E) : (-L2E);
#if HAS32
  f16x8 w0f[2], w1i[2], w1r[2];   // [tile]; x32 frag: k = 8q+j
#pragma unroll
  for (int t = 0; t < 2; ++t) {
    const int R = gA * 32 + 4 * (2 * wq + t) + (m >> 2);
    const int i0 = R * 32 + 8 * q;
    uint4 v;
    v.x = ldpacks<BFM>(s0, i0 + 0, sw); v.y = ldpacks<BFM>(s0, i0 + 2, sw);
    v.z = ldpacks<BFM>(s0, i0 + 4, sw); v.w = ldpacks<BFM>(s0, i0 + 6, sw);
    w0f[t] = __builtin_bit_cast(f16x8, v);
    v.x = ldpacks<BFM>(sA, i0 + 0, sw); v.y = ldpacks<BFM>(sA, i0 + 2, sw);
    v.z = ldpacks<BFM>(sA, i0 + 4, sw); v.w = ldpacks<BFM>(sA, i0 + 6, sw);
    w1i[t] = __builtin_bit_cast(f16x8, v);
    v.x = ldpacks<BFM>(sB, i0 + 0, sw); v.y = ldpacks<BFM>(sB, i0 + 2, sw);
    v.z = ldpacks<BFM>(sB, i0 + 4, sw); v.w = ldpacks<BFM>(sB, i0 + 6, sw);
    w1r[t] = __builtin_bit_cast(f16x8, v);
  }
#else
  f16x4 w0f[2][2], w1i[2][2], w1r[2][2];  // x16 frags: k = 16s+4q+j
#pragma unroll
  for (int t = 0; t < 2; ++t) {
    const int R = gA * 32 + 4 * (2 * wq + t) + (m >> 2);
#pragma unroll
    for (int s = 0; s < 2; ++s) {
      const int i0 = R * 32 + 16 * s + 4 * q;
      u32x2v v;
      v.x = ldpacks<BFM>(s0, i0, sw); v.y = ldpacks<BFM>(s0, i0 + 2, sw);
      w0f[t][s] = __builtin_bit_cast(f16x4, v);
      v.x = ldpacks<BFM>(sA, i0, sw); v.y = ldpacks<BFM>(sA, i0 + 2, sw);
      w1i[t][s] = __builtin_bit_cast(f16x4, v);
      v.x = ldpacks<BFM>(sB, i0, sw); v.y = ldpacks<BFM>(sB, i0 + 2, sw);
      w1r[t][s] = __builtin_bit_cast(f16x4, v);
    }
  }
#endif
  // ---- per-lane combine constants: ONE cell per lane per layer ----
  const int cA = 8 * wq + q, cB = cA + 4;
  const int cM = half ? cB : cA;
  float wxv[4], b0v[4], b1v[4];
#pragma unroll
  for (int r = 0; r < 4; ++r) {
    const float sg = (r == 2) ? (2.0f * L2E) : (-L2E);
    wxv[r] = ldin<BFM>(pwx, r * 32 + cM) * sg;
    b0v[r] = ldin<BFM>(pb0, r * 32 + cM) * sg;
    b1v[r] = ldin<BFM>(pb1, r * 32 + cM) * sg;
  }
  const float wlM = ldin<BFM>(Wlin, dirv * 32 + cM);
  const float blv = ldin<BFM>(blin, 0);
  const int fut = *futp;

  // zero LDS
  for (int i = tid; i < 2 * 2 * 16 * ROWDW; i += NT) h0l[i] = 0u;
  for (int i = tid; i < 2 * 16 * ROWDW; i += NT) hf1l[i] = 0u;
  if (tid < 128) po[tid] = 0.f;
  __syncthreads();

  float c0 = 0.f, c1 = 0.f, pr = 0.f;
  float x_cur = ldxg<BFM>(xg, (dirv ? ((fut + 1) & (SS - 1)) : 0) * BB + xb);

  for (int u = 0; u <= SS + 2; ++u) {
    const int par_w = u & 1, par_r = (u + 1) & 1;
    const int nidx = dirv ? ((fut - u) & (SS - 1)) : ((u + 1 < SS) ? u + 1 : SS - 1);
    const float x_nxt = ldxg<BFM>(xg, nidx * BB + xb);  // vmcnt-only: in flight

    // ---- shared B-frag reads: h0(prev) feeds BOTH L0-rec and L1-inp ----
    const u32* hbp = &h0l[((dirv * 2 + par_r) * 16 + m) * ROWDW];
    const u32* hrp = &hf1l[(par_r * 16 + m) * ROWDW];
    f32x4 a0, a1, d0, d1;
    const f32x4 z = {0.f, 0.f, 0.f, 0.f};
#if HAS32
    f16x8 Bs = __builtin_bit_cast(f16x8, *(const uint4*)(hbp + 4 * q));
    f16x8 Br = __builtin_bit_cast(f16x8, *(const uint4*)(hrp + 4 * q));
    a0 = mfma32(w0f[0], Bs, z);
    a1 = mfma32(w0f[1], Bs, z);
    d0 = mfma32(w1r[0], Br, mfma32(w1i[0], Bs, z));
    d1 = mfma32(w1r[1], Br, mfma32(w1i[1], Bs, z));
#else
    {
      const u32x2v* hb2 = (const u32x2v*)hbp;
      const u32x2v* hr2 = (const u32x2v*)hrp;
      f16x4 Bs0 = __builtin_bit_cast(f16x4, hb2[q]);
      f16x4 Bs1 = __builtin_bit_cast(f16x4, hb2[4 + q]);
      f16x4 Br0 = __builtin_bit_cast(f16x4, hr2[q]);
      f16x4 Br1 = __builtin_bit_cast(f16x4, hr2[4 + q]);
      a0 = mfma16(w0f[0][1], Bs1, mfma16(w0f[0][0], Bs0, z));
      a1 = mfma16(w0f[1][1], Bs1, mfma16(w0f[1][0], Bs0, z));
      d0 = mfma16(w1i[0][1], Bs1, mfma16(w1i[0][0], Bs0, z));
      d1 = mfma16(w1i[1][1], Bs1, mfma16(w1i[1][0], Bs0, z));
      d0 = mfma16(w1r[0][1], Br1, mfma16(w1r[0][0], Br0, d0));
      d1 = mfma16(w1r[1][1], Br1, mfma16(w1r[1][0], Br0, d1));
    }
#endif

    // ---- head finalize (wave 0): emit out(u-3) from po[par_r], pure DPP ----
    if (wv == 0 && u >= 3) {
      float pz = po[par_r * 64 + lane];   // [b = lane>>3][w = lane&7]
      DPPADD(pz, 0x111, 0xf);             // row_shr:1
      DPPADD(pz, 0x112, 0xf);             // row_shr:2
      DPPADD(pz, 0x114, 0xf);             // row_shr:4 -> lane 8b+7 = sum over w
      if ((lane & 7) == 7) {
        float o = pz + blv;
        size_t pos = (size_t)(gb8 + (lane >> 3)) * SS + (size_t)(u - 3);
        if (BFM) ((u16*)outp_g)[pos] = f2bf(o);
        else     ((float*)outp_g)[pos] = o;
      }
    }

    // ---- L0 combine: one cell per lane (tile-B quad swapped to upper half) ----
    float acc[4];
#pragma unroll
    for (int r = 0; r < 4; ++r) {
      float swp = dppswap8(a1[r]);
      acc[r] = (half ? swp : a0[r]) + fmaf(wxv[r], x_cur, b0v[r]);
    }
    float hn0 = combine(acc, c0);
    if (u == 0 && dirv) { hn0 = 0.f; c0 = 0.f; }   // bwd t'=-1 garbage
    ((u16*)&h0l[((dirv * 2 + par_w) * 16 + bM) * ROWDW])[cM] = f16bits(hn0);

    // ---- L1 combine ----
#pragma unroll
    for (int r = 0; r < 4; ++r) {
      float swp = dppswap8(d1[r]);
      acc[r] = (half ? swp : d0[r]) + b1v[r];
    }
    float hn1 = combine(acc, c1);
    if (dirv) { if (u <= 1) c1 = 0.f; }            // bwd t'=-2,-1 garbage
    else      { if (u == 0) c1 = 0.f; }            // fwd t=-1 garbage
    if (!dirv && u >= 1)                           // publish hf1(u-1)
      ((u16*)&hf1l[(par_w * 16 + bM) * ROWDW])[cM] = f16bits(hn1);

    // ---- head partials for t=u-2 (pure VALU reduction; batch = lane&7) ----
    float v = wlM * (dirv ? hn1 : pr);
    pr = hn1;
    DPPADD(v, 0x128, 0xf);      // + lane^8  (halves)
    v = plswap16_add(v);        // + lane^16 (q bit 0)
    v = plswap32_add(v);        // + lane^32 (q bit 1)
    if (lane < 8) po[par_w * 64 + lane * 8 + wv] = v;  // [b][w]

    BARRIER();
    x_cur = x_nxt;
  }
}

__global__ void __launch_bounds__(NT, 2) lstm_kernel(
    const void* __restrict__ xg,
    const void* Wih_f0, const void* Whh_f0, const void* b_f0,
    const void* Wih_f1, const void* Whh_f1, const void* b_f1,
    const void* Wih_b0, const void* Whh_b0, const void* b_b0,
    const void* Wih_b1, const void* Whh_b1, const void* b_b1,
    const void* Wlin, const void* blin, const int* __restrict__ futp,
    void* __restrict__ outp) {
  __shared__ __align__(16) u32 h0s[2 * 2 * 16 * ROWDW];
  __shared__ __align__(16) u32 hf1s[2 * 16 * ROWDW];
  __shared__ __align__(16) float pos_[2 * 64];

  // dtype detection (uniform): bf16-pairs read as fp32 implausible as N(0,1)
  bool bfm;
  {
    const float* xf = (const float*)xg;
    int bad = 0;
    for (int i = 0; i < 64; ++i) {
      float a = fabsf(xf[i]);
      bool ok = (a == 0.0f) || (a > 1e-8f && a < 1e4f);
      if (!ok) bad = 1;
    }
    bfm = (bad != 0);
  }

  if (bfm)
    run<true>(xg, Wih_f0, Whh_f0, b_f0, Wih_f1, Whh_f1, b_f1,
              Wih_b0, Whh_b0, b_b0, Wih_b1, Whh_b1, b_b1,
              Wlin, blin, futp, outp, h0s, hf1s, pos_,
              threadIdx.x, blockIdx.x);
  else
    run<false>(xg, Wih_f0, Whh_f0, b_f0, Wih_f1, Whh_f1, b_f1,
               Wih_b0, Whh_b0, b_b0, Wih_b1, Whh_b1, b_b1,
               Wlin, blin, futp, outp, h0s, hf1s, pos_,
               threadIdx.x, blockIdx.x);
}

extern "C" void kernel_launch(void* const* d_in, const int* in_sizes, int n_in,
                              void* d_out, int out_size, void* d_ws, size_t ws_size,
                              hipStream_t stream) {
  (void)in_sizes; (void)n_in; (void)out_size; (void)d_ws; (void)ws_size;
  lstm_kernel<<<dim3(GRID), dim3(NT), 0, stream>>>(
      d_in[0], d_in[1], d_in[2], d_in[3], d_in[4], d_in[5], d_in[6],
      d_in[7], d_in[8], d_in[9], d_in[10], d_in[11], d_in[12],
      d_in[13], d_in[14], (const int*)d_in[15], d_out);
}

// Round 13
// 632.408 us; speedup vs baseline: 1.6310x; 1.1687x over previous
//
#include <hip/hip_runtime.h>

#define SS 1024
#define BB 2048
#define NT 256     // 4 waves: 0=L0f, 1=L0b, 2=L1f, 3=L1b+head
#define GRID 256   // 8 batches/block -> 2048; 1 block/CU
#define G8 8
#define KS 8       // scan steps per phase (one barrier per KS steps)
#define NPH 130    // 128 + 2 drain phases (L1b lags 2 phases)
#define ROWDW 20   // dwords per LDS batch-row (80 B): b128-aligned, conflict-free
#define SLOTDW (8 * ROWDW)
#define H0F 0
#define H0B (32 * SLOTDW)
#define HF1O (64 * SLOTDW)
#define TOTDW (96 * SLOTDW)   // 61.4 KB static LDS

typedef unsigned int u32;
typedef unsigned short u16;
typedef _Float16 f16x8 __attribute__((ext_vector_type(8)));
typedef float f32x4 __attribute__((ext_vector_type(4)));
typedef int int2v __attribute__((ext_vector_type(2)));
typedef __fp16 fp16x2 __attribute__((ext_vector_type(2)));

#define L2E 1.4426950408889634f

// lgkmcnt drain + barrier (vmcnt NOT drained: global x prefetch stays in flight)
#define BARRIER() asm volatile("s_waitcnt lgkmcnt(0)\n\ts_barrier" ::: "memory")

// DPP add of cross-lane shifted copy (pure VALU)
#define DPPADD(v, ctrl, rm)                                                   \
  do {                                                                        \
    int _t = __builtin_amdgcn_update_dpp(0, __float_as_int(v), (ctrl), (rm),  \
                                         0xf, true);                          \
    (v) += __int_as_float(_t);                                                \
  } while (0)

// ---------- helpers ----------
__device__ __forceinline__ u16 f2bf(float f) {
  u32 u = __float_as_uint(f);
  return (u16)((u + 0x7fffu + ((u >> 16) & 1u)) >> 16);
}
template<bool BFM>
__device__ __forceinline__ float ldin(const void* p, int i) {
  if (BFM) { u16 v = ((const u16*)p)[i]; return __uint_as_float(((u32)v) << 16); }
  return ((const float*)p)[i];
}
// explicit global-addrspace load: vmcnt-only, survives lgkmcnt barrier drain
template<bool BFM>
__device__ __forceinline__ float ldxg(const void* p, unsigned int i) {
  if (BFM) {
    const __attribute__((address_space(1))) u16* g =
        (const __attribute__((address_space(1))) u16*)(unsigned long long)p;
    return __uint_as_float(((u32)g[i]) << 16);
  }
  const __attribute__((address_space(1))) float* g =
      (const __attribute__((address_space(1))) float*)(unsigned long long)p;
  return g[i];
}
__device__ __forceinline__ u32 packrtz(float lo, float hi) {
#if __has_builtin(__builtin_amdgcn_cvt_pkrtz)
  fp16x2 h = __builtin_amdgcn_cvt_pkrtz(lo, hi);
  return __builtin_bit_cast(u32, h);
#else
  _Float16 ha = (_Float16)lo, hb = (_Float16)hi;
  return (u32)__builtin_bit_cast(u16, ha) | ((u32)__builtin_bit_cast(u16, hb) << 16);
#endif
}
__device__ __forceinline__ float exp2fast(float x) {
#if __has_builtin(__builtin_amdgcn_exp2f)
  return __builtin_amdgcn_exp2f(x);
#else
  return __expf(x * 0.6931471805599453f);
#endif
}
// pre-acts PRE-SCALED: sigmoid gates by -log2e, tanh gate by +2log2e
__device__ __forceinline__ float combine(const float acc[4], float& c) {
  float ig = __builtin_amdgcn_rcpf(1.0f + exp2fast(acc[0]));
  float fg = __builtin_amdgcn_rcpf(1.0f + exp2fast(acc[1]));
  float gg = 1.0f - 2.0f * __builtin_amdgcn_rcpf(1.0f + exp2fast(acc[2]));
  float og = __builtin_amdgcn_rcpf(1.0f + exp2fast(acc[3]));
  c = fg * c + ig * gg;
  float th = 1.0f - 2.0f * __builtin_amdgcn_rcpf(1.0f + exp2fast((2.0f * L2E) * c));
  return og * th;
}
__device__ __forceinline__ u16 f16bits(float x) {   // RNE f32->f16
  _Float16 h = (_Float16)x;
  return __builtin_bit_cast(u16, h);
}
__device__ __forceinline__ u32 packrne(float lo, float hi) {
  return (u32)f16bits(lo) | ((u32)f16bits(hi) << 16);
}
__device__ __forceinline__ float plswap16_add(float v) {  // + lane^16 (R12-verified)
#if __has_builtin(__builtin_amdgcn_permlane16_swap)
  int2v r = __builtin_amdgcn_permlane16_swap(__float_as_int(v),
                                             __float_as_int(v), false, false);
  return __int_as_float(r.x) + __int_as_float(r.y);
#else
  return v + __shfl_xor(v, 16, 64);
#endif
}
__device__ __forceinline__ float plswap32_add(float v) {  // + lane^32 (R12-verified)
#if __has_builtin(__builtin_amdgcn_permlane32_swap)
  int2v r = __builtin_amdgcn_permlane32_swap(__float_as_int(v),
                                             __float_as_int(v), false, false);
  return __int_as_float(r.x) + __int_as_float(r.y);
#else
  return v + __shfl_xor(v, 32, 64);
#endif
}
__device__ __forceinline__ f32x4 mfma32(f16x8 a, f16x8 b, f32x4 c) {
#if __has_builtin(__builtin_amdgcn_mfma_f32_16x16x32_f16)
  return __builtin_amdgcn_mfma_f32_16x16x32_f16(a, b, c, 0, 0, 0);
#else
  // fallback: split into two x16 (k = 8q+j order preserved by halves)
  typedef _Float16 f16x4 __attribute__((ext_vector_type(4)));
  f16x4 a0 = {a[0],a[1],a[2],a[3]}, a1 = {a[4],a[5],a[6],a[7]};
  f16x4 b0 = {b[0],b[1],b[2],b[3]}, b1 = {b[4],b[5],b[6],b[7]};
  c = __builtin_amdgcn_mfma_f32_16x16x16f16(a0, b0, c, 0, 0, 0);
  return __builtin_amdgcn_mfma_f32_16x16x16f16(a1, b1, c, 0, 0, 0);
#endif
}

// ===========================================================================
// Layout algebra (row perm + k perm σ, applied identically to A and B):
//  Row perm (outputs): W~ row 16T+mr  <- orig row R = (mr&3)*32 + 4T + (mr>>2)
//    -> D(tile T, row 4q+r, col m) = cell 4T+q, gate r, batch m&7 (cols x2 dup)
//    -> lane (m,q), half h=m>>3 combines cells c_k = 16h + 4k + q (tiles 4h+k)
//  k perm σ (inputs): cell c = 16hc + 4kc + qc  ->  k-slot 8*(2hc+(kc>>1)) + 2qc+(kc&1)
//    -> producer lane (m,q): pack (v0,v1)->dw at row b, dword 8h+q;
//                            (v2,v3)-> dword 8h+4+q
//    -> consumer lane (m,q): B-frag = b128 at row m&7, dwords 4q..4q+3
//    -> A staging element j of q-group: orig col c_in = 16(q>>1)+8(q&1)+4(j&1)+(j>>1)
// Rings (u32): h0f[32 slots] h0b[32] hf1[32]; slot = scan & 31. Span audit:
//  h0f: write s@phase s/8, read (L1f) @+1  -> dist<=15  OK
//  h0b: read (L1b) @+2                      -> dist<=23  OK
//  hf1: L1f writes s@phase s/8+1; L1b reads s@+2; same-phase ranges disjoint OK
// Phase p: L0 steps [8p,8p+7] (p<128); L1f steps-8 (1<=p<=128); L1b steps-16 (p>=2).
// ===========================================================================
template<bool BFM>
__device__ __forceinline__ void run(
    const void* xg,
    const void* Wih_f0, const void* Whh_f0, const void* b_f0,
    const void* Wih_f1, const void* Whh_f1, const void* b_f1,
    const void* Wih_b0, const void* Whh_b0, const void* b_b0,
    const void* Wih_b1, const void* Whh_b1, const void* b_b1,
    const void* Wlin, const void* blin, const int* futp, void* outp_g,
    u32* ring, int tid, int bid) {
  const int wv = tid >> 6, lane = tid & 63;
  const int m = lane & 15, q = lane >> 4;
  const int b = m & 7, h = m >> 3;
  const int gb8 = bid * G8;
  const bool isL0 = wv < 2;
  const int dirv = wv & 1;                 // L0: 0=f 1=b

  const void* Wr = (wv == 0) ? Whh_f0 : (wv == 1) ? Whh_b0
                 : (wv == 2) ? Whh_f1 : Whh_b1;
  const void* Wi = (wv == 3) ? Wih_b1 : Wih_f1;     // L1 only
  const void* pb = (wv == 0) ? b_f0 : (wv == 1) ? b_b0
                 : (wv == 2) ? b_f1 : b_b1;
  const void* px = dirv ? Wih_b0 : Wih_f0;          // L0 only

  // ---- A-fragment staging with row perm + σ (element-wise; one-time) ----
  const int B0 = 16 * (q >> 1) + 8 * (q & 1);
  const int gA = m & 3;
  const float sw = (gA == 2) ? (2.0f * L2E) : (-L2E);
  f16x8 wr8[8], wi8[8];
#pragma unroll
  for (int T = 0; T < 8; ++T) {
    const int R = gA * 32 + 4 * T + (m >> 2);
    u32 vr[4], vi[4];
#pragma unroll
    for (int e = 0; e < 4; ++e) {
      vr[e] = packrtz(ldin<BFM>(Wr, R * 32 + B0 + e) * sw,
                      ldin<BFM>(Wr, R * 32 + B0 + 4 + e) * sw);
      vi[e] = isL0 ? 0u
                   : packrtz(ldin<BFM>(Wi, R * 32 + B0 + e) * sw,
                             ldin<BFM>(Wi, R * 32 + B0 + 4 + e) * sw);
    }
    uint4 t0 = {vr[0], vr[1], vr[2], vr[3]};
    uint4 t1 = {vi[0], vi[1], vi[2], vi[3]};
    wr8[T] = __builtin_bit_cast(f16x8, t0);
    wi8[T] = __builtin_bit_cast(f16x8, t1);
  }
  // ---- per-lane combine constants: 4 cells c_k = 16h + 4k + q ----
  float bv[4][4], wxv[4][4], cs[4], wlb[4], wlf[8];
#pragma unroll
  for (int k = 0; k < 4; ++k) {
    const int ck = 16 * h + 4 * k + q;
    cs[k] = 0.f;
#pragma unroll
    for (int r = 0; r < 4; ++r) {
      const float sg = (r == 2) ? (2.0f * L2E) : (-L2E);
      bv[k][r] = ldin<BFM>(pb, r * 32 + ck) * sg;
      wxv[k][r] = isL0 ? ldin<BFM>(px, r * 32 + ck) * sg : 0.f;
    }
    wlb[k] = (wv == 3) ? ldin<BFM>(Wlin, 32 + ck) : 0.f;
  }
#pragma unroll
  for (int j = 0; j < 8; ++j)   // wlf in σ-order: cell = B0 + 4*(j&1) + (j>>1)
    wlf[j] = (wv == 3 && m < 8)
                 ? ldin<BFM>(Wlin, B0 + 4 * (j & 1) + (j >> 1)) : 0.f;
  const float blv = ldin<BFM>(blin, 0);
  const int fut = *futp;

  // zero rings (step -1 reads hit zeros)
  for (int i = tid; i < TOTDW; i += NT) ring[i] = 0u;
  __syncthreads();

  // x preload (L0 waves): current-phase values in xc, next-phase in flight
  float xc[KS], xn[KS];
#pragma unroll
  for (int j = 0; j < KS; ++j) {
    int idx = dirv ? ((fut - j) & (SS - 1)) : j;
    xc[j] = isL0 ? ldxg<BFM>(xg, idx * BB + gb8 + b) : 0.f;
  }

  const f32x4 z = {0.f, 0.f, 0.f, 0.f};
  for (int p = 0; p < NPH; ++p) {
    if (isL0) {
      // prefetch next phase's x (vmcnt-only; survives barrier)
#pragma unroll
      for (int j = 0; j < KS; ++j) {
        int sn = KS * (p + 1) + j;
        int idx = dirv ? ((fut - sn) & (SS - 1)) : ((sn < SS) ? sn : SS - 1);
        xn[j] = ldxg<BFM>(xg, idx * BB + gb8 + b);
      }
      if (p < SS / KS) {
        const int base = dirv ? H0B : H0F;
#pragma unroll
        for (int j = 0; j < KS; ++j) {
          const int s = KS * p + j;
          const u32* rp = ring + base + ((s - 1) & 31) * SLOTDW + b * ROWDW + 4 * q;
          f16x8 Bf = __builtin_bit_cast(f16x8, *(const uint4*)rp);
          f32x4 D[8];
#pragma unroll
          for (int T = 0; T < 8; ++T) D[T] = mfma32(wr8[T], Bf, z);
          float hh[4];
#pragma unroll
          for (int k = 0; k < 4; ++k) {
            float acc[4];
#pragma unroll
            for (int r = 0; r < 4; ++r) {
              float dv = h ? D[4 + k][r] : D[k][r];   // tile 4h+k, static idx
              acc[r] = dv + fmaf(wxv[k][r], xc[j], bv[k][r]);
            }
            hh[k] = combine(acc, cs[k]);
          }
          u32* wp = ring + base + (s & 31) * SLOTDW + b * ROWDW;
          wp[8 * h + q]     = packrne(hh[0], hh[1]);   // σ positions
          wp[8 * h + 4 + q] = packrne(hh[2], hh[3]);
        }
      }
#pragma unroll
      for (int j = 0; j < KS; ++j) xc[j] = xn[j];
    } else if (wv == 2) {
      // L1f: steps KS*(p-1)+j; inp=h0f (stable), rec=own hf1 (intra-wave)
      if (p >= 1 && p <= SS / KS) {
#pragma unroll
        for (int j = 0; j < KS; ++j) {
          const int s = KS * (p - 1) + j;
          const u32* ip = ring + H0F + (s & 31) * SLOTDW + b * ROWDW + 4 * q;
          const u32* rp = ring + HF1O + ((s - 1) & 31) * SLOTDW + b * ROWDW + 4 * q;
          f16x8 Bi = __builtin_bit_cast(f16x8, *(const uint4*)ip);
          f16x8 Br = __builtin_bit_cast(f16x8, *(const uint4*)rp);
          f32x4 D[8];
#pragma unroll
          for (int T = 0; T < 8; ++T)
            D[T] = mfma32(wr8[T], Br, mfma32(wi8[T], Bi, z));
          float hh[4];
#pragma unroll
          for (int k = 0; k < 4; ++k) {
            float acc[4];
#pragma unroll
            for (int r = 0; r < 4; ++r) {
              float dv = h ? D[4 + k][r] : D[k][r];
              acc[r] = dv + bv[k][r];
            }
            hh[k] = combine(acc, cs[k]);
          }
          u32* wp = ring + HF1O + (s & 31) * SLOTDW + b * ROWDW;
          wp[8 * h + q]     = packrne(hh[0], hh[1]);
          wp[8 * h + 4 + q] = packrne(hh[2], hh[3]);
        }
      }
    } else {
      // L1b + head: steps KS*(p-2)+j; inp=h0b, rec=hf1(s) (ref bug); head fused
      if (p >= 2) {
#pragma unroll
        for (int j = 0; j < KS; ++j) {
          const int s = KS * (p - 2) + j;
          const u32* ip = ring + H0B + (s & 31) * SLOTDW + b * ROWDW + 4 * q;
          const u32* rp = ring + HF1O + (s & 31) * SLOTDW + b * ROWDW + 4 * q;
          f16x8 Bi = __builtin_bit_cast(f16x8, *(const uint4*)ip);
          f16x8 Br = __builtin_bit_cast(f16x8, *(const uint4*)rp);
          f32x4 D[8];
#pragma unroll
          for (int T = 0; T < 8; ++T)
            D[T] = mfma32(wr8[T], Br, mfma32(wi8[T], Bi, z));
          float hh[4];
#pragma unroll
          for (int k = 0; k < 4; ++k) {
            float acc[4];
#pragma unroll
            for (int r = 0; r < 4; ++r) {
              float dv = h ? D[4 + k][r] : D[k][r];
              acc[r] = dv + bv[k][r];
            }
            hh[k] = combine(acc, cs[k]);
          }
          // head(s) = wlb.hb1(s) + wlf.hf1(s) + blv ; hf1(s) = Br (in σ-order)
          float pl = fmaf(wlb[0], hh[0],
                     fmaf(wlb[1], hh[1],
                     fmaf(wlb[2], hh[2], wlb[3] * hh[3])));
#pragma unroll
          for (int jj = 0; jj < 8; ++jj) pl = fmaf(wlf[jj], (float)Br[jj], pl);
          DPPADD(pl, 0x128, 0xf);     // + lane^8  (h)
          pl = plswap16_add(pl);      // + lane^16 (q bit 0)
          pl = plswap32_add(pl);      // + lane^32 (q bit 1)
          if (lane < 8) {
            float o = pl + blv;
            size_t pos = (size_t)(gb8 + lane) * SS + (size_t)s;
            if (BFM) ((u16*)outp_g)[pos] = f2bf(o);
            else     ((float*)outp_g)[pos] = o;
          }
        }
      }
    }
    BARRIER();
  }
}

__global__ void __launch_bounds__(NT, 1) lstm_kernel(
    const void* __restrict__ xg,
    const void* Wih_f0, const void* Whh_f0, const void* b_f0,
    const void* Wih_f1, const void* Whh_f1, const void* b_f1,
    const void* Wih_b0, const void* Whh_b0, const void* b_b0,
    const void* Wih_b1, const void* Whh_b1, const void* b_b1,
    const void* Wlin, const void* blin, const int* __restrict__ futp,
    void* __restrict__ outp) {
  __shared__ __align__(16) u32 rings[TOTDW];

  // dtype detection (uniform): bf16-pairs read as fp32 implausible as N(0,1)
  bool bfm;
  {
    const float* xf = (const float*)xg;
    int bad = 0;
    for (int i = 0; i < 64; ++i) {
      float a = fabsf(xf[i]);
      bool ok = (a == 0.0f) || (a > 1e-8f && a < 1e4f);
      if (!ok) bad = 1;
    }
    bfm = (bad != 0);
  }

  if (bfm)
    run<true>(xg, Wih_f0, Whh_f0, b_f0, Wih_f1, Whh_f1, b_f1,
              Wih_b0, Whh_b0, b_b0, Wih_b1, Whh_b1, b_b1,
              Wlin, blin, futp, outp, rings, threadIdx.x, blockIdx.x);
  else
    run<false>(xg, Wih_f0, Whh_f0, b_f0, Wih_f1, Whh_f1, b_f1,
               Wih_b0, Whh_b0, b_b0, Wih_b1, Whh_b1, b_b1,
               Wlin, blin, futp, outp, rings, threadIdx.x, blockIdx.x);
}

extern "C" void kernel_launch(void* const* d_in, const int* in_sizes, int n_in,
                              void* d_out, int out_size, void* d_ws, size_t ws_size,
                              hipStream_t stream) {
  (void)in_sizes; (void)n_in; (void)out_size; (void)d_ws; (void)ws_size;
  lstm_kernel<<<dim3(GRID), dim3(NT), 0, stream>>>(
      d_in[0], d_in[1], d_in[2], d_in[3], d_in[4], d_in[5], d_in[6],
      d_in[7], d_in[8], d_in[9], d_in[10], d_in[11], d_in[12],
      d_in[13], d_in[14], (const int*)d_in[15], d_out);
}